// Round 6
// baseline (3268.794 us; speedup 1.0000x reference)
//
#include <hip/hip_runtime.h>
#include <hip/hip_bf16.h>

// Problem constants (from reference)
#define L_SEQ   2048
#define DMODEL  1024
#define DINNER  2048
#define DSTATE  16
#define DTRANK  64
#define DCONV   4
#define NLAYER  4
#define XDIM    96   // DTRANK + 2*DSTATE
#define CHUNK   32
#define NCHUNK  (L_SEQ / CHUNK)   // 64
#define KSPLIT  16                // x_proj split-K factor
#define KSPLIT_O 4                // out_proj split-K factor
#define LOG2E   1.4426950408889634f

#define NBLK 1024                 // persistent grid: 4 blocks/CU x 256 CUs
#define NTHR 256
#define SLOT_STRIDE 16            // 64 B per flag (own cacheline)
#define NSLOT_INTS (NBLK * SLOT_STRIDE)   // 16384 ints = 64 KB per array

typedef __attribute__((ext_vector_type(8))) short bf16x8;
typedef __attribute__((ext_vector_type(4))) float f32x4;

__device__ __forceinline__ float bf2f(unsigned short u) {
    union { unsigned int i; float f; } v; v.i = ((unsigned int)u) << 16; return v.f;
}
__device__ __forceinline__ unsigned short f2bf(float f) {
    union { float f; unsigned int i; } v; v.f = f;
    unsigned int x = v.i;
    unsigned int r = (x + 0x7fffu + ((x >> 16) & 1u)) >> 16;  // RTNE
    return (unsigned short)r;
}
__device__ __forceinline__ float ldin(const void* p, size_t idx, bool bf) {
    return bf ? bf2f(((const unsigned short*)p)[idx]) : ((const float*)p)[idx];
}
__device__ __forceinline__ void gload16(const unsigned short* g, unsigned short* l) {
    __builtin_amdgcn_global_load_lds(
        (const __attribute__((address_space(1))) unsigned int*)g,
        (__attribute__((address_space(3))) unsigned int*)l, 16, 0, 0);
}

// ---------------------------------------------------------------------------
// Grid barrier v3: FULLY distributed.  Round-4/5 lesson: ~1000 agents
// spinning on ONE cacheline (the release word `gen`) serialize ~80ns each at
// the cross-XCD coherence point => ~80us per release, independent of the
// arrival mechanism (fetch_add vs per-slot stores gave identical time AND
// identical 1.1GB spin FETCH traffic).  v3 gives every block BOTH a private
// arrival line and a private RELEASE line: block 0 gathers arrivals (distinct
// lines), then its 256 threads fan the release out to 1023 distinct lines.
// No line ever has more than one spinner.
// ---------------------------------------------------------------------------
__device__ __forceinline__ void gbar(int* slots, int* rel, int tgt) {
    __syncthreads();
    const int tid = threadIdx.x;
    if (blockIdx.x == 0) {
        #pragma unroll
        for (int k = 0; k < NBLK / NTHR; ++k) {
            const int s = k * NTHR + tid;
            if (s != 0) {
                while (__hip_atomic_load(slots + s * SLOT_STRIDE, __ATOMIC_RELAXED,
                                         __HIP_MEMORY_SCOPE_AGENT) < tgt)
                    __builtin_amdgcn_s_sleep(2);
                (void)__hip_atomic_load(slots + s * SLOT_STRIDE, __ATOMIC_ACQUIRE,
                                        __HIP_MEMORY_SCOPE_AGENT);
            }
        }
        __syncthreads();   // all acquires done -> releases below publish them
        #pragma unroll
        for (int k = 0; k < NBLK / NTHR; ++k) {
            const int s = k * NTHR + tid;
            if (s != 0)
                __hip_atomic_store(rel + s * SLOT_STRIDE, tgt,
                                   __ATOMIC_RELEASE, __HIP_MEMORY_SCOPE_AGENT);
        }
        // block 0 proceeds; its own acquires cover all producers.
    } else {
        if (tid == 0) {
            __hip_atomic_store(slots + blockIdx.x * SLOT_STRIDE, tgt,
                               __ATOMIC_RELEASE, __HIP_MEMORY_SCOPE_AGENT);
            while (__hip_atomic_load(rel + blockIdx.x * SLOT_STRIDE, __ATOMIC_RELAXED,
                                     __HIP_MEMORY_SCOPE_AGENT) < tgt)
                __builtin_amdgcn_s_sleep(16);
            (void)__hip_atomic_load(rel + blockIdx.x * SLOT_STRIDE, __ATOMIC_ACQUIRE,
                                    __HIP_MEMORY_SCOPE_AGENT);
        }
        __syncthreads();
    }
}

// ---------------------------------------------------------------------------
// Init: zero arrival+release lines, detect dtype.  A_log[0]=log(1)=0 for fp32.
// ---------------------------------------------------------------------------
__global__ __launch_bounds__(256) void k_init(
    const unsigned int* __restrict__ Alog_u32, int* __restrict__ flag,
    int* __restrict__ flags_base)   // slots (64KB) + rel (64KB) contiguous
{
    if (blockIdx.x < 128) {
        flags_base[blockIdx.x * 256 + threadIdx.x] = 0;
    } else if (threadIdx.x == 0) {
        *flag = (Alog_u32[0] != 0u) ? 1 : 0;
    }
}

// ---------------------------------------------------------------------------
// Weight cast fp32 -> bf16, ALL layers in one launch (grid.y = layer).
// No-op when inputs already bf16 (GEMMs then read original pointers).
// ---------------------------------------------------------------------------
#define N_IP (2 * DINNER * DMODEL)   // 4,194,304
#define N_XP (XDIM * DINNER)         //   196,608
#define N_DT (DINNER * DTRANK)       //   131,072
#define N_OP (DMODEL * DINNER)       // 2,097,152
#define CAST_BLOCKS ((N_IP + N_XP + N_DT + N_OP) / 4 / 256)   // 6464 exact

__global__ __launch_bounds__(256) void k_castall(
    const void* __restrict__ ipw, const void* __restrict__ xpw,
    const void* __restrict__ dtw, const void* __restrict__ opw,
    unsigned short* __restrict__ w_ip, unsigned short* __restrict__ w_xp,
    unsigned short* __restrict__ w_dt, unsigned short* __restrict__ w_op,
    const int* __restrict__ flagp)
{
    if (*flagp) return;
    const int layer = blockIdx.y;
    int i = (blockIdx.x * 256 + threadIdx.x) * 4;
    const float* src; unsigned short* dst;
    if (i < N_IP)                { src = (const float*)ipw + (size_t)layer * N_IP + i; dst = w_ip + (size_t)layer * N_IP + i; }
    else if ((i -= N_IP) < N_XP) { src = (const float*)xpw + (size_t)layer * N_XP + i; dst = w_xp + (size_t)layer * N_XP + i; }
    else if ((i -= N_XP) < N_DT) { src = (const float*)dtw + (size_t)layer * N_DT + i; dst = w_dt + (size_t)layer * N_DT + i; }
    else if ((i -= N_DT) < N_OP) { src = (const float*)opw + (size_t)layer * N_OP + i; dst = w_op + (size_t)layer * N_OP + i; }
    else return;
    const float4 v = *(const float4*)src;
    ushort4 o;
    o.x = f2bf(v.x); o.y = f2bf(v.y); o.z = f2bf(v.z); o.w = f2bf(v.w);
    *(ushort4*)dst = o;
}

// ---------------------------------------------------------------------------
// Device GEMM: C[M,N] = A[M,K]_bf16 * W[N,K]^T_bf16, one 64x128 tile per call.
// 256 thr, BK=32, triple-buffered LDS, depth-2 prefetch, counted vmcnt(3),
// one block-barrier per K-step.  Conflict-free swizzle (granule kg^((r>>1)&3))
// via pre-swizzled global source; LDS dest linear.
// mode: 0 fp32 C, 1 softplus+bias fp32, 2 bf16 C.
// ---------------------------------------------------------------------------
__device__ __forceinline__ void gemm_dev(
    int tid, int n0, int m0, int k0, int Kslice,
    const unsigned short* __restrict__ A, int lda,
    const unsigned short* __restrict__ W, int ldw,
    void* __restrict__ C, size_t czoff, int ldc, int N,
    const void* __restrict__ bias, size_t boff, int mode, bool bf,
    unsigned short* lA, unsigned short* lB)   // lA: 3*2048, lB: 3*4096 shorts
{
    const int w    = tid >> 6;
    const int lane = tid & 63;
    const int wn = w * 32;                        // wave owns 64(M) x 32(N)
    const int m16 = lane & 15, kg = lane >> 4;
    const int swz = (kg ^ ((m16 >> 1) & 3)) * 8;  // read-side swizzle (shorts)

    const int rB0 = w * 32 + (lane >> 2);
    const int rB1 = rB0 + 16;
    const int rA  = w * 16 + (lane >> 2);
    const int sk  = ((lane & 3) ^ ((lane >> 3) & 3)) * 8;   // shorts
    const int nrB0 = (n0 + rB0 < N) ? (n0 + rB0) : 0;   // clamp OOB rows to 0
    const int nrB1 = (n0 + rB1 < N) ? (n0 + rB1) : 0;
    const unsigned short* aSrc  = A + (size_t)(m0 + rA) * lda + k0 + sk;
    const unsigned short* bSrc0 = W + (size_t)nrB0 * ldw + k0 + sk;
    const unsigned short* bSrc1 = W + (size_t)nrB1 * ldw + k0 + sk;
    const int ldB0 = w * 1024, ldB1 = ldB0 + 512;
    const int ldA  = w * 512;

    f32x4 acc[4][2];
    #pragma unroll
    for (int i = 0; i < 4; ++i)
        #pragma unroll
        for (int j = 0; j < 2; ++j)
            acc[i][j] = (f32x4){0.f, 0.f, 0.f, 0.f};

    #define STAGE(bq, kk) do { \
        gload16(aSrc  + (kk), lA + (bq) * 2048 + ldA); \
        gload16(bSrc0 + (kk), lB + (bq) * 4096 + ldB0); \
        gload16(bSrc1 + (kk), lB + (bq) * 4096 + ldB1); \
    } while (0)

    const int nt = Kslice >> 5;
    STAGE(0, 0);
    if (nt > 1) {
        STAGE(1, 32);
        asm volatile("s_waitcnt vmcnt(3)" ::: "memory");
    } else {
        asm volatile("s_waitcnt vmcnt(0)" ::: "memory");
    }
    __builtin_amdgcn_s_barrier();
    __builtin_amdgcn_sched_barrier(0);

    int cur = 0, nx2 = 2;
    for (int t = 0; t < nt; ++t) {
        if (t + 2 < nt) STAGE(nx2, (t + 2) * 32);
        bf16x8 af[4], bfr[2];
        #pragma unroll
        for (int i = 0; i < 4; ++i)
            af[i] = *(const bf16x8*)&lA[cur * 2048 + (i * 16 + m16) * 32 + swz];
        #pragma unroll
        for (int j = 0; j < 2; ++j)
            bfr[j] = *(const bf16x8*)&lB[cur * 4096 + (wn + j * 16 + m16) * 32 + swz];
        #pragma unroll
        for (int i = 0; i < 4; ++i)
            #pragma unroll
            for (int j = 0; j < 2; ++j)
                acc[i][j] = __builtin_amdgcn_mfma_f32_16x16x32_bf16(af[i], bfr[j], acc[i][j], 0, 0, 0);
        if (t + 1 < nt) {
            if (t + 2 < nt) asm volatile("s_waitcnt vmcnt(3)" ::: "memory");
            else            asm volatile("s_waitcnt vmcnt(0)" ::: "memory");
            __builtin_amdgcn_s_barrier();
            __builtin_amdgcn_sched_barrier(0);
        }
        cur = (cur == 2) ? 0 : cur + 1;
        nx2 = (nx2 == 2) ? 0 : nx2 + 1;
    }
    #undef STAGE

    const int rowb = (lane >> 4) * 4;
    float* Cf = (float*)C + czoff;
    unsigned short* Ch = (unsigned short*)C;
    #pragma unroll
    for (int j = 0; j < 2; ++j) {
        const int col = n0 + wn + j * 16 + m16;
        if (col < N) {
            float bv = 0.f;
            if (mode == 1) bv = ldin(bias, boff + col, bf);
            #pragma unroll
            for (int i = 0; i < 4; ++i) {
                #pragma unroll
                for (int r = 0; r < 4; ++r) {
                    const int row = m0 + i * 16 + rowb + r;
                    float v = acc[i][j][r];
                    if (mode == 1) { v += bv; v = (v > 20.f) ? v : log1pf(__expf(v)); }
                    if (mode == 2) Ch[(size_t)row * ldc + col] = f2bf(v);
                    else           Cf[(size_t)row * ldc + col] = v;
                }
            }
        }
    }
}

// ---------------------------------------------------------------------------
// Persistent megakernel: all 4 layers + final, grid barriers between phases.
// ---------------------------------------------------------------------------
struct MegaArgs {
    const void* hs; const void* normw;
    const void* ipw; const void* cw; const void* cb; const void* xpw;
    const void* dtw; const void* dtb; const void* Alog; const void* Dp; const void* opw;
    const unsigned short* w_ip; const unsigned short* w_xp;
    const unsigned short* w_dt; const unsigned short* w_op;
    float* resid; unsigned short* hn_bf; unsigned short* xz_bf; unsigned short* uc_bf;
    float* xdblb; unsigned short* xdbl_bf; float* deltab; float* partsX;
    float* hlocb; float* sdeltab; unsigned short* y_bf; float* partsO;
    void* out;
    int* flagp; int* slots; int* rel;
};

__global__ __launch_bounds__(NTHR, 4) void k_mega(MegaArgs a)
{
    __shared__ unsigned short lA[3][64 * 32];    // 12 KB
    __shared__ unsigned short lB[3][128 * 32];   // 24 KB
    __shared__ float red[4];
    const int bid = blockIdx.x;
    const int tid = threadIdx.x;
    const bool bf = (*a.flagp != 0);
    const int lane = tid & 63, wv = tid >> 6;
    int bt = 0;   // monotonic barrier target

    for (int i = 0; i < NLAYER; ++i) {
        const size_t o_ipw = (size_t)i * N_IP;
        const size_t o_xpw = (size_t)i * N_XP;
        const size_t o_dtw = (size_t)i * N_DT;
        const size_t o_opw = (size_t)i * N_OP;
        const size_t o_al  = (size_t)i * DINNER * DSTATE;
        const unsigned short* Wip = (bf ? (const unsigned short*)a.ipw : a.w_ip) + o_ipw;
        const unsigned short* Wxp = (bf ? (const unsigned short*)a.xpw : a.w_xp) + o_xpw;
        const unsigned short* Wdt = (bf ? (const unsigned short*)a.dtw : a.w_dt) + o_dtw;
        const unsigned short* Wop = (bf ? (const unsigned short*)a.opw : a.w_op) + o_opw;

        // ---- P1: addnorm (+4-way out_proj partial add), 2 rows/block ----
        for (int rr = 0; rr < 2; ++rr) {
            const int row = bid * 2 + rr;
            const int col = tid * 4;
            const size_t base = (size_t)row * DMODEL + col;
            float r[4];
            if (i == 0) {
                if (bf) {
                    const ushort4 v = *(const ushort4*)((const unsigned short*)a.hs + base);
                    r[0] = bf2f(v.x); r[1] = bf2f(v.y); r[2] = bf2f(v.z); r[3] = bf2f(v.w);
                } else {
                    const float4 v = *(const float4*)((const float*)a.hs + base);
                    r[0] = v.x; r[1] = v.y; r[2] = v.z; r[3] = v.w;
                }
            } else {
                const float4 p0 = *(const float4*)(a.partsO + base);
                const float4 p1 = *(const float4*)(a.partsO + (size_t)1 * L_SEQ * DMODEL + base);
                const float4 p2 = *(const float4*)(a.partsO + (size_t)2 * L_SEQ * DMODEL + base);
                const float4 p3 = *(const float4*)(a.partsO + (size_t)3 * L_SEQ * DMODEL + base);
                const float4 rv = *(const float4*)(a.resid + base);
                r[0] = p0.x + p1.x + p2.x + p3.x + rv.x;
                r[1] = p0.y + p1.y + p2.y + p3.y + rv.y;
                r[2] = p0.z + p1.z + p2.z + p3.z + rv.z;
                r[3] = p0.w + p1.w + p2.w + p3.w + rv.w;
            }
            *(float4*)(a.resid + base) = make_float4(r[0], r[1], r[2], r[3]);
            float ss = r[0]*r[0] + r[1]*r[1] + r[2]*r[2] + r[3]*r[3];
            #pragma unroll
            for (int o = 32; o > 0; o >>= 1) ss += __shfl_down(ss, o);
            if (lane == 0) red[wv] = ss;
            __syncthreads();
            const float total = red[0] + red[1] + red[2] + red[3];
            const float scale = rsqrtf(total * (1.0f / DMODEL) + 1e-5f);
            const size_t woff = (size_t)i * DMODEL;
            const float w0 = ldin(a.normw, woff + col + 0, bf), w1 = ldin(a.normw, woff + col + 1, bf);
            const float w2 = ldin(a.normw, woff + col + 2, bf), w3 = ldin(a.normw, woff + col + 3, bf);
            ushort4 o;
            o.x = f2bf(r[0] * scale * w0); o.y = f2bf(r[1] * scale * w1);
            o.z = f2bf(r[2] * scale * w2); o.w = f2bf(r[3] * scale * w3);
            *(ushort4*)(a.hn_bf + base) = o;
            __syncthreads();
        }
        gbar(a.slots, a.rel, ++bt);

        // ---- P2: in_proj (1024 blocks = 32n x 32m) ----
        gemm_dev(tid, (bid & 31) * 128, (bid >> 5) * 64, 0, DMODEL,
                 a.hn_bf, DMODEL, Wip, DMODEL,
                 a.xz_bf, 0, 2 * DINNER, 2 * DINNER, nullptr, 0, 2, bf,
                 &lA[0][0], &lB[0][0]);
        gbar(a.slots, a.rel, ++bt);

        // ---- P3: conv (own region) + x_proj split-K (512 blocks = 32m x 16z) ----
        if (bid < 512) {
            const int m = bid & 31, z = bid >> 5;
            const int dd = z * 128 + (tid & 127);
            const size_t cwo = (size_t)i * DINNER * DCONV + (size_t)dd * 4;
            const float w0 = ldin(a.cw, cwo + 0, bf), w1 = ldin(a.cw, cwo + 1, bf);
            const float w2 = ldin(a.cw, cwo + 2, bf), w3 = ldin(a.cw, cwo + 3, bf);
            const float cbv = ldin(a.cb, (size_t)i * DINNER + dd, bf);
            for (int it = 0; it < 32; ++it) {
                const int l = m * 64 + it * 2 + (tid >> 7);
                float acc = cbv;
                if (l >= 3) acc = fmaf(bf2f(a.xz_bf[(size_t)(l - 3) * (2 * DINNER) + dd]), w0, acc);
                if (l >= 2) acc = fmaf(bf2f(a.xz_bf[(size_t)(l - 2) * (2 * DINNER) + dd]), w1, acc);
                if (l >= 1) acc = fmaf(bf2f(a.xz_bf[(size_t)(l - 1) * (2 * DINNER) + dd]), w2, acc);
                acc = fmaf(bf2f(a.xz_bf[(size_t)l * (2 * DINNER) + dd]), w3, acc);
                const float sig = 1.f / (1.f + __expf(-acc));
                a.uc_bf[(size_t)l * DINNER + dd] = f2bf(acc * sig);
            }
            __syncthreads();   // own uc writes complete before own gload16 reads
            gemm_dev(tid, 0, m * 64, z * 128, DINNER / KSPLIT,
                     a.uc_bf, DINNER, Wxp, DINNER,
                     a.partsX, (size_t)z * L_SEQ * XDIM, XDIM, XDIM, nullptr, 0, 0, bf,
                     &lA[0][0], &lB[0][0]);
        }
        gbar(a.slots, a.rel, ++bt);

        // ---- P4: x_proj reduce (768 blocks) ----
        if (bid < 768) {
            const int idx = bid * 256 + tid;   // < 196,608
            float s = 0.f;
            #pragma unroll
            for (int z = 0; z < KSPLIT; ++z)
                s += a.partsX[(size_t)z * L_SEQ * XDIM + idx];
            a.xdblb[idx] = s;
            a.xdbl_bf[idx] = f2bf(s);
        }
        gbar(a.slots, a.rel, ++bt);

        // ---- P5: dt_proj + softplus (512 blocks = 16n x 32m) ----
        if (bid < 512) {
            gemm_dev(tid, (bid >> 5) * 128, (bid & 31) * 64, 0, DTRANK,
                     a.xdbl_bf, XDIM, Wdt, DTRANK,
                     a.deltab, 0, DINNER, DINNER, a.dtb, (size_t)i * DINNER, 1, bf,
                     &lA[0][0], &lB[0][0]);
        }
        gbar(a.slots, a.rel, ++bt);

        // ---- P6: scan1 (512 blocks = 8 dblk x 64 chunks, 256 d/block) ----
        if (bid < 512) {
            float (*sB)[DSTATE] = (float(*)[DSTATE])&lA[0][0];
            const int d = (bid & 7) * 256 + tid;
            const int c = bid >> 3;
            const int t0 = c * CHUNK;
            float A2[DSTATE];
            #pragma unroll
            for (int n = 0; n < DSTATE; ++n)
                A2[n] = -__expf(ldin(a.Alog, o_al + (size_t)d * DSTATE + n, bf)) * LOG2E;
            #pragma unroll
            for (int r = 0; r < 2; ++r) {
                const int idx = r * 256 + tid;   // 0..511
                sB[idx >> 4][idx & 15] = a.xdblb[(size_t)(t0 + (idx >> 4)) * XDIM + DTRANK + (idx & 15)];
            }
            __syncthreads();
            float h[DSTATE];
            #pragma unroll
            for (int n = 0; n < DSTATE; ++n) h[n] = 0.f;
            float sd = 0.f;
            float dcur = a.deltab[(size_t)t0 * DINNER + d];
            float ucur = bf2f(a.uc_bf[(size_t)t0 * DINNER + d]);
            for (int ti = 0; ti < CHUNK; ++ti) {
                float dnx = 0.f, unx = 0.f;
                if (ti < CHUNK - 1) {
                    const size_t nxt = (size_t)(t0 + ti + 1) * DINNER + d;
                    dnx = a.deltab[nxt];
                    unx = bf2f(a.uc_bf[nxt]);
                }
                sd += dcur;
                const float du = dcur * ucur;
                #pragma unroll
                for (int n = 0; n < DSTATE; ++n) {
                    const float dA = exp2f(dcur * A2[n]);
                    h[n] = fmaf(dA, h[n], du * sB[ti][n]);
                }
                dcur = dnx; ucur = unx;
            }
            float* hp = a.hlocb + ((size_t)c * DINNER + d) * DSTATE;
            #pragma unroll
            for (int n = 0; n < DSTATE; n += 4)
                *(float4*)(hp + n) = make_float4(h[n], h[n+1], h[n+2], h[n+3]);
            a.sdeltab[(size_t)c * DINNER + d] = sd;
        }
        gbar(a.slots, a.rel, ++bt);

        // ---- P7: scan2 (128 blocks, 8-deep ping-pong prefetch) ----
        if (bid < 128) {
            const int gid = bid * 256 + tid;
            const int d = gid >> 4, n = gid & 15;
            const float A2 = -__expf(ldin(a.Alog, o_al + (size_t)d * DSTATE + n, bf)) * LOG2E;
            const size_t hstep = (size_t)DINNER * DSTATE;
            float* hp = a.hlocb + (size_t)d * DSTATE + n;
            const float* sp = a.sdeltab + d;
            float hA[8], sA[8], hB[8], sB2[8];
            #pragma unroll
            for (int j = 0; j < 8; ++j) {
                hA[j] = hp[(size_t)j * hstep];
                sA[j] = sp[(size_t)j * DINNER];
            }
            float carry = 0.f;
            for (int g = 0; g < 8; g += 2) {
                const int cA = g * 8, cB = cA + 8, cN = cA + 16;
                #pragma unroll
                for (int j = 0; j < 8; ++j) {
                    hB[j]  = hp[(size_t)(cB + j) * hstep];
                    sB2[j] = sp[(size_t)(cB + j) * DINNER];
                }
                #pragma unroll
                for (int j = 0; j < 8; ++j) {
                    hp[(size_t)(cA + j) * hstep] = carry;
                    carry = fmaf(exp2f(A2 * sA[j]), carry, hA[j]);
                }
                if (g + 2 < 8) {
                    #pragma unroll
                    for (int j = 0; j < 8; ++j) {
                        hA[j] = hp[(size_t)(cN + j) * hstep];
                        sA[j] = sp[(size_t)(cN + j) * DINNER];
                    }
                }
                #pragma unroll
                for (int j = 0; j < 8; ++j) {
                    hp[(size_t)(cB + j) * hstep] = carry;
                    carry = fmaf(exp2f(A2 * sB2[j]), carry, hB[j]);
                }
            }
        }
        gbar(a.slots, a.rel, ++bt);

        // ---- P8: scan3 (512 blocks) ----
        if (bid < 512) {
            float (*sBC)[2 * DSTATE] = (float(*)[2 * DSTATE])&lA[0][0];
            const int d = (bid & 7) * 256 + tid;
            const int c = bid >> 3;
            const int t0 = c * CHUNK;
            float A2[DSTATE];
            #pragma unroll
            for (int n = 0; n < DSTATE; ++n)
                A2[n] = -__expf(ldin(a.Alog, o_al + (size_t)d * DSTATE + n, bf)) * LOG2E;
            const float Dv = ldin(a.Dp, (size_t)i * DINNER + d, bf);
            #pragma unroll
            for (int r = 0; r < 4; ++r) {
                const int idx = r * 256 + tid;   // 0..1023
                sBC[idx >> 5][idx & 31] = a.xdblb[(size_t)(t0 + (idx >> 5)) * XDIM + DTRANK + (idx & 31)];
            }
            __syncthreads();
            float h[DSTATE];
            const float* hp = a.hlocb + ((size_t)c * DINNER + d) * DSTATE;
            #pragma unroll
            for (int n = 0; n < DSTATE; n += 4) {
                const float4 v = *(const float4*)(hp + n);
                h[n] = v.x; h[n+1] = v.y; h[n+2] = v.z; h[n+3] = v.w;
            }
            float dcur = a.deltab[(size_t)t0 * DINNER + d];
            float ucur = bf2f(a.uc_bf[(size_t)t0 * DINNER + d]);
            float zcur = bf2f(a.xz_bf[(size_t)t0 * (2 * DINNER) + DINNER + d]);
            for (int ti = 0; ti < CHUNK; ++ti) {
                float dnx = 0.f, unx = 0.f, znx = 0.f;
                if (ti < CHUNK - 1) {
                    const size_t nxt = (size_t)(t0 + ti + 1) * DINNER + d;
                    dnx = a.deltab[nxt];
                    unx = bf2f(a.uc_bf[nxt]);
                    znx = bf2f(a.xz_bf[(size_t)(t0 + ti + 1) * (2 * DINNER) + DINNER + d]);
                }
                const float du = dcur * ucur;
                float dot = 0.f;
                #pragma unroll
                for (int n = 0; n < DSTATE; ++n) {
                    const float dA = exp2f(dcur * A2[n]);
                    h[n] = fmaf(dA, h[n], du * sBC[ti][n]);
                    dot = fmaf(h[n], sBC[ti][DSTATE + n], dot);
                }
                const float sig = 1.f / (1.f + __expf(-zcur));
                a.y_bf[(size_t)(t0 + ti) * DINNER + d] = f2bf((dot + ucur * Dv) * (zcur * sig));
                dcur = dnx; ucur = unx; zcur = znx;
            }
        }
        gbar(a.slots, a.rel, ++bt);

        // ---- P9: out_proj split-K=4 (1024 blocks = 8n x 32m x 4z) ----
        {
            const int z = bid >> 8, rem = bid & 255;
            gemm_dev(tid, (rem & 7) * 128, (rem >> 3) * 64, z * (DINNER / KSPLIT_O), DINNER / KSPLIT_O,
                     a.y_bf, DINNER, Wop, DINNER,
                     a.partsO, (size_t)z * L_SEQ * DMODEL, DMODEL, DMODEL, nullptr, 0, 0, bf,
                     &lA[0][0], &lB[0][0]);
        }
        gbar(a.slots, a.rel, ++bt);
    }

    // ---- final: out = sum(parts) + resid ----
    {
        const int base = (bid * 256 + tid) * 8;
        #pragma unroll
        for (int hh = 0; hh < 2; ++hh) {
            const int i4 = base + hh * 4;
            const float4 p0 = *(const float4*)(a.partsO + i4);
            const float4 p1 = *(const float4*)(a.partsO + (size_t)1 * L_SEQ * DMODEL + i4);
            const float4 p2 = *(const float4*)(a.partsO + (size_t)2 * L_SEQ * DMODEL + i4);
            const float4 p3 = *(const float4*)(a.partsO + (size_t)3 * L_SEQ * DMODEL + i4);
            const float4 rv = *(const float4*)(a.resid + i4);
            const float o0 = p0.x + p1.x + p2.x + p3.x + rv.x;
            const float o1 = p0.y + p1.y + p2.y + p3.y + rv.y;
            const float o2 = p0.z + p1.z + p2.z + p3.z + rv.z;
            const float o3 = p0.w + p1.w + p2.w + p3.w + rv.w;
            if (bf) {
                ushort4 o;
                o.x = f2bf(o0); o.y = f2bf(o1); o.z = f2bf(o2); o.w = f2bf(o3);
                *(ushort4*)((unsigned short*)a.out + i4) = o;
            } else {
                *(float4*)((float*)a.out + i4) = make_float4(o0, o1, o2, o3);
            }
        }
    }
}

extern "C" void kernel_launch(void* const* d_in, const int* in_sizes, int n_in,
                              void* d_out, int out_size, void* d_ws, size_t ws_size,
                              hipStream_t stream)
{
    const void* hs    = d_in[0];
    const void* normw = d_in[1];
    const void* ipw   = d_in[2];
    const void* cw    = d_in[3];
    const void* cb    = d_in[4];
    const void* xpw   = d_in[5];
    const void* dtw   = d_in[6];
    const void* dtb   = d_in[7];
    const void* Alog  = d_in[8];
    const void* Dp    = d_in[9];
    const void* opw   = d_in[10];

    // fp32 region (~68 MB)
    float* ws      = (float*)d_ws;
    float* resid   = ws;                                         // 2,097,152
    float* xdblb   = resid   + (size_t)L_SEQ * DMODEL;           //   196,608
    float* deltab  = xdblb   + (size_t)L_SEQ * XDIM;             // 4,194,304 (partsX overlay)
    float* hlocb   = deltab  + (size_t)L_SEQ * DINNER;           // 2,097,152
    float* sdeltab = hlocb   + (size_t)NCHUNK * DINNER * DSTATE; //   131,072
    float* partsO  = sdeltab + (size_t)NCHUNK * DINNER;          // 8,388,608 (4 slices)
    // bf16 region (~91 MB)
    unsigned short* hn_bf   = (unsigned short*)(partsO + (size_t)KSPLIT_O * L_SEQ * DMODEL);
    unsigned short* xz_bf   = hn_bf   + (size_t)L_SEQ * DMODEL;
    unsigned short* uc_bf   = xz_bf   + (size_t)L_SEQ * 2 * DINNER;
    unsigned short* xdbl_bf = uc_bf   + (size_t)L_SEQ * DINNER;
    unsigned short* y_bf    = xdbl_bf + (size_t)L_SEQ * XDIM;
    unsigned short* w_ip    = y_bf    + (size_t)L_SEQ * DINNER;
    unsigned short* w_xp    = w_ip    + (size_t)NLAYER * N_IP;
    unsigned short* w_dt    = w_xp    + (size_t)NLAYER * N_XP;
    unsigned short* w_op    = w_dt    + (size_t)NLAYER * N_DT;
    int*            tail    = (int*)(w_op + (size_t)NLAYER * N_OP);
    int* flagp = tail;               // own cacheline
    int* slots = tail + 64;          // NSLOT_INTS ints (64 KB), 64B lines
    int* rel   = slots + NSLOT_INTS; // NSLOT_INTS ints (64 KB), 64B lines

    float* partsX = deltab;   // KSPLIT*L*XDIM = 3,145,728 <= 4,194,304

    k_init<<<129, 256, 0, stream>>>((const unsigned int*)Alog, flagp, slots);
    k_castall<<<dim3(CAST_BLOCKS, NLAYER), 256, 0, stream>>>(
        ipw, xpw, dtw, opw, w_ip, w_xp, w_dt, w_op, flagp);

    MegaArgs ma;
    ma.hs = hs; ma.normw = normw; ma.ipw = ipw; ma.cw = cw; ma.cb = cb;
    ma.xpw = xpw; ma.dtw = dtw; ma.dtb = dtb; ma.Alog = Alog; ma.Dp = Dp; ma.opw = opw;
    ma.w_ip = w_ip; ma.w_xp = w_xp; ma.w_dt = w_dt; ma.w_op = w_op;
    ma.resid = resid; ma.hn_bf = hn_bf; ma.xz_bf = xz_bf; ma.uc_bf = uc_bf;
    ma.xdblb = xdblb; ma.xdbl_bf = xdbl_bf; ma.deltab = deltab; ma.partsX = partsX;
    ma.hlocb = hlocb; ma.sdeltab = sdeltab; ma.y_bf = y_bf; ma.partsO = partsO;
    ma.out = d_out; ma.flagp = flagp; ma.slots = slots; ma.rel = rel;

    // Cooperative launch guarantees co-residency for the grid barrier.
    // During graph capture (or on API failure) fall back to a plain launch:
    // grid == exact 4-blocks/CU capacity (enforced by __launch_bounds__(256,4)),
    // so all 1024 blocks are co-resident by construction.
    hipStreamCaptureStatus cs = hipStreamCaptureStatusNone;
    (void)hipStreamIsCapturing(stream, &cs);
    bool done = false;
    if (cs == hipStreamCaptureStatusNone) {
        void* kp[] = { (void*)&ma };
        hipError_t e = hipLaunchCooperativeKernel((const void*)k_mega,
                                                  dim3(NBLK), dim3(NTHR), kp, 0, stream);
        if (e == hipSuccess) done = true;
        else (void)hipGetLastError();
    }
    if (!done) k_mega<<<NBLK, NTHR, 0, stream>>>(ma);
}

// Round 7
// 965.625 us; speedup vs baseline: 3.3852x; 3.3852x over previous
//
#include <hip/hip_runtime.h>
#include <hip/hip_bf16.h>

// Problem constants (from reference)
#define L_SEQ   2048
#define DMODEL  1024
#define DINNER  2048
#define DSTATE  16
#define DTRANK  64
#define DCONV   4
#define NLAYER  4
#define XDIM    96   // DTRANK + 2*DSTATE
#define CHUNK   32
#define NCHUNK  (L_SEQ / CHUNK)   // 64
#define KSPLIT  16                // x_proj split-K factor
#define KSPLIT_O 4                // out_proj split-K factor
#define LOG2E   1.4426950408889634f

typedef __attribute__((ext_vector_type(8))) short bf16x8;
typedef __attribute__((ext_vector_type(4))) float f32x4;

__device__ __forceinline__ float bf2f(unsigned short u) {
    union { unsigned int i; float f; } v; v.i = ((unsigned int)u) << 16; return v.f;
}
__device__ __forceinline__ unsigned short f2bf(float f) {
    union { float f; unsigned int i; } v; v.f = f;
    unsigned int x = v.i;
    unsigned int r = (x + 0x7fffu + ((x >> 16) & 1u)) >> 16;  // RTNE
    return (unsigned short)r;
}
__device__ __forceinline__ float ldin(const void* p, size_t idx, bool bf) {
    return bf ? bf2f(((const unsigned short*)p)[idx]) : ((const float*)p)[idx];
}
__device__ __forceinline__ void gload16(const unsigned short* g, unsigned short* l) {
    __builtin_amdgcn_global_load_lds(
        (const __attribute__((address_space(1))) unsigned int*)g,
        (__attribute__((address_space(3))) unsigned int*)l, 16, 0, 0);
}

// ---------------------------------------------------------------------------
// Dtype detector: A_log[0] = log(1) = 0.  fp32 -> first u32 == 0x00000000.
// ---------------------------------------------------------------------------
__global__ void k_detect(const unsigned int* __restrict__ Alog_u32, int* __restrict__ flag) {
    *flag = (Alog_u32[0] != 0u) ? 1 : 0;
}

// ---------------------------------------------------------------------------
// Weight cast fp32 -> bf16, ALL layers in one launch (grid.y = layer).
// No-op when inputs already bf16 (GEMMs then read original pointers).
// ---------------------------------------------------------------------------
#define N_IP (2 * DINNER * DMODEL)   // 4,194,304
#define N_XP (XDIM * DINNER)         //   196,608
#define N_DT (DINNER * DTRANK)       //   131,072
#define N_OP (DMODEL * DINNER)       // 2,097,152
#define CAST_BLOCKS ((N_IP + N_XP + N_DT + N_OP) / 4 / 256)   // 6464 exact

__global__ __launch_bounds__(256) void k_castall(
    const void* __restrict__ ipw, const void* __restrict__ xpw,
    const void* __restrict__ dtw, const void* __restrict__ opw,
    unsigned short* __restrict__ w_ip, unsigned short* __restrict__ w_xp,
    unsigned short* __restrict__ w_dt, unsigned short* __restrict__ w_op,
    const int* __restrict__ flagp)
{
    if (*flagp) return;
    const int layer = blockIdx.y;
    int i = (blockIdx.x * 256 + threadIdx.x) * 4;
    const float* src; unsigned short* dst;
    if (i < N_IP)                { src = (const float*)ipw + (size_t)layer * N_IP + i; dst = w_ip + (size_t)layer * N_IP + i; }
    else if ((i -= N_IP) < N_XP) { src = (const float*)xpw + (size_t)layer * N_XP + i; dst = w_xp + (size_t)layer * N_XP + i; }
    else if ((i -= N_XP) < N_DT) { src = (const float*)dtw + (size_t)layer * N_DT + i; dst = w_dt + (size_t)layer * N_DT + i; }
    else if ((i -= N_DT) < N_OP) { src = (const float*)opw + (size_t)layer * N_OP + i; dst = w_op + (size_t)layer * N_OP + i; }
    else return;
    const float4 v = *(const float4*)src;
    ushort4 o;
    o.x = f2bf(v.x); o.y = f2bf(v.y); o.z = f2bf(v.z); o.w = f2bf(v.w);
    *(ushort4*)dst = o;
}

// ---------------------------------------------------------------------------
// Fused 4-way out_proj partial add + residual add + RMSNorm -> bf16.
// first==1: read hs input.  first==0: r = parts0..3 + resid.
// ---------------------------------------------------------------------------
__global__ __launch_bounds__(256) void k_addnorm(
    const float* __restrict__ parts, const void* __restrict__ hs,
    float* __restrict__ resid, unsigned short* __restrict__ hnorm,
    const void* __restrict__ w, size_t woff, int first,
    const int* __restrict__ flagp)
{
    const bool bf = (*flagp != 0);
    const int row = blockIdx.x;
    const int col = threadIdx.x * 4;
    const size_t base = (size_t)row * DMODEL + col;
    float r[4];
    if (first) {
        if (bf) {
            const ushort4 v = *(const ushort4*)((const unsigned short*)hs + base);
            r[0] = bf2f(v.x); r[1] = bf2f(v.y); r[2] = bf2f(v.z); r[3] = bf2f(v.w);
        } else {
            const float4 v = *(const float4*)((const float*)hs + base);
            r[0] = v.x; r[1] = v.y; r[2] = v.z; r[3] = v.w;
        }
    } else {
        const float4 p0 = *(const float4*)(parts + base);
        const float4 p1 = *(const float4*)(parts + (size_t)1 * L_SEQ * DMODEL + base);
        const float4 p2 = *(const float4*)(parts + (size_t)2 * L_SEQ * DMODEL + base);
        const float4 p3 = *(const float4*)(parts + (size_t)3 * L_SEQ * DMODEL + base);
        const float4 rv = *(const float4*)(resid + base);
        r[0] = p0.x + p1.x + p2.x + p3.x + rv.x;
        r[1] = p0.y + p1.y + p2.y + p3.y + rv.y;
        r[2] = p0.z + p1.z + p2.z + p3.z + rv.z;
        r[3] = p0.w + p1.w + p2.w + p3.w + rv.w;
    }
    *(float4*)(resid + base) = make_float4(r[0], r[1], r[2], r[3]);
    float ss = r[0]*r[0] + r[1]*r[1] + r[2]*r[2] + r[3]*r[3];
    #pragma unroll
    for (int o = 32; o > 0; o >>= 1) ss += __shfl_down(ss, o);
    __shared__ float red[4];
    const int lane = threadIdx.x & 63, wv = threadIdx.x >> 6;
    if (lane == 0) red[wv] = ss;
    __syncthreads();
    const float total = red[0] + red[1] + red[2] + red[3];
    const float scale = rsqrtf(total * (1.0f / DMODEL) + 1e-5f);
    const float w0 = ldin(w, woff + col + 0, bf), w1 = ldin(w, woff + col + 1, bf);
    const float w2 = ldin(w, woff + col + 2, bf), w3 = ldin(w, woff + col + 3, bf);
    ushort4 o;
    o.x = f2bf(r[0] * scale * w0); o.y = f2bf(r[1] * scale * w1);
    o.z = f2bf(r[2] * scale * w2); o.w = f2bf(r[3] * scale * w3);
    *(ushort4*)(hnorm + base) = o;
}

// ---------------------------------------------------------------------------
// Device GEMM: C[M,N] = A[M,K]_bf16 * W[N,K]^T_bf16, one 64x128 tile per call.
// 256 thr, BK=32, triple-buffered LDS, depth-2 prefetch, counted vmcnt(3),
// one block-barrier per K-step.  Conflict-free swizzle (granule kg^((r>>1)&3))
// via pre-swizzled global source; LDS dest linear.
// mode: 0 fp32 C, 1 softplus+bias fp32, 2 bf16 C.
// ---------------------------------------------------------------------------
__device__ __forceinline__ void gemm_dev(
    int tid, int n0, int m0, int k0, int Kslice,
    const unsigned short* __restrict__ A, int lda,
    const unsigned short* __restrict__ W, int ldw,
    void* __restrict__ C, size_t czoff, int ldc, int N,
    const void* __restrict__ bias, size_t boff, int mode, bool bf,
    unsigned short* lA, unsigned short* lB)   // lA: 3*2048, lB: 3*4096 shorts
{
    const int w    = tid >> 6;
    const int lane = tid & 63;
    const int wn = w * 32;                        // wave owns 64(M) x 32(N)
    const int m16 = lane & 15, kg = lane >> 4;
    const int swz = (kg ^ ((m16 >> 1) & 3)) * 8;  // read-side swizzle (shorts)

    const int rB0 = w * 32 + (lane >> 2);
    const int rB1 = rB0 + 16;
    const int rA  = w * 16 + (lane >> 2);
    const int sk  = ((lane & 3) ^ ((lane >> 3) & 3)) * 8;   // shorts
    const int nrB0 = (n0 + rB0 < N) ? (n0 + rB0) : 0;   // clamp OOB rows to 0
    const int nrB1 = (n0 + rB1 < N) ? (n0 + rB1) : 0;
    const unsigned short* aSrc  = A + (size_t)(m0 + rA) * lda + k0 + sk;
    const unsigned short* bSrc0 = W + (size_t)nrB0 * ldw + k0 + sk;
    const unsigned short* bSrc1 = W + (size_t)nrB1 * ldw + k0 + sk;
    const int ldB0 = w * 1024, ldB1 = ldB0 + 512;
    const int ldA  = w * 512;

    f32x4 acc[4][2];
    #pragma unroll
    for (int i = 0; i < 4; ++i)
        #pragma unroll
        for (int j = 0; j < 2; ++j)
            acc[i][j] = (f32x4){0.f, 0.f, 0.f, 0.f};

    #define STAGE(bq, kk) do { \
        gload16(aSrc  + (kk), lA + (bq) * 2048 + ldA); \
        gload16(bSrc0 + (kk), lB + (bq) * 4096 + ldB0); \
        gload16(bSrc1 + (kk), lB + (bq) * 4096 + ldB1); \
    } while (0)

    const int nt = Kslice >> 5;
    STAGE(0, 0);
    if (nt > 1) {
        STAGE(1, 32);
        asm volatile("s_waitcnt vmcnt(3)" ::: "memory");
    } else {
        asm volatile("s_waitcnt vmcnt(0)" ::: "memory");
    }
    __builtin_amdgcn_s_barrier();
    __builtin_amdgcn_sched_barrier(0);

    int cur = 0, nx2 = 2;
    for (int t = 0; t < nt; ++t) {
        if (t + 2 < nt) STAGE(nx2, (t + 2) * 32);
        bf16x8 af[4], bfr[2];
        #pragma unroll
        for (int i = 0; i < 4; ++i)
            af[i] = *(const bf16x8*)&lA[cur * 2048 + (i * 16 + m16) * 32 + swz];
        #pragma unroll
        for (int j = 0; j < 2; ++j)
            bfr[j] = *(const bf16x8*)&lB[cur * 4096 + (wn + j * 16 + m16) * 32 + swz];
        #pragma unroll
        for (int i = 0; i < 4; ++i)
            #pragma unroll
            for (int j = 0; j < 2; ++j)
                acc[i][j] = __builtin_amdgcn_mfma_f32_16x16x32_bf16(af[i], bfr[j], acc[i][j], 0, 0, 0);
        if (t + 1 < nt) {
            if (t + 2 < nt) asm volatile("s_waitcnt vmcnt(3)" ::: "memory");
            else            asm volatile("s_waitcnt vmcnt(0)" ::: "memory");
            __builtin_amdgcn_s_barrier();
            __builtin_amdgcn_sched_barrier(0);
        }
        cur = (cur == 2) ? 0 : cur + 1;
        nx2 = (nx2 == 2) ? 0 : nx2 + 1;
    }
    #undef STAGE

    const int rowb = (lane >> 4) * 4;
    float* Cf = (float*)C + czoff;
    unsigned short* Ch = (unsigned short*)C;
    #pragma unroll
    for (int j = 0; j < 2; ++j) {
        const int col = n0 + wn + j * 16 + m16;
        if (col < N) {
            float bv = 0.f;
            if (mode == 1) bv = ldin(bias, boff + col, bf);
            #pragma unroll
            for (int i = 0; i < 4; ++i) {
                #pragma unroll
                for (int r = 0; r < 4; ++r) {
                    const int row = m0 + i * 16 + rowb + r;
                    float v = acc[i][j][r];
                    if (mode == 1) { v += bv; v = (v > 20.f) ? v : log1pf(__expf(v)); }
                    if (mode == 2) Ch[(size_t)row * ldc + col] = f2bf(v);
                    else           Cf[(size_t)row * ldc + col] = v;
                }
            }
        }
    }
}

// ---------------------------------------------------------------------------
// Standalone GEMM wrapper: grid (n-tiles, m-tiles, split-K slices).
// ---------------------------------------------------------------------------
__global__ __launch_bounds__(256) void k_gemm_mfma(
    const unsigned short* __restrict__ A, int lda,
    const void* __restrict__ Worig, size_t woff,
    const unsigned short* __restrict__ Wconv, int ldw,
    void* __restrict__ C, int ldc, size_t czstride,
    int N, int Kslice,
    const void* __restrict__ bias, size_t boff, int mode,
    const int* __restrict__ flagp)
{
    __shared__ unsigned short lA[3][64 * 32];    // 12 KB
    __shared__ unsigned short lB[3][128 * 32];   // 24 KB
    const bool bf = (*flagp != 0);
    const unsigned short* W = bf ? ((const unsigned short*)Worig + woff) : Wconv;
    gemm_dev(threadIdx.x, blockIdx.x * 128, blockIdx.y * 64,
             blockIdx.z * Kslice, Kslice,
             A, lda, W, ldw, C, (size_t)blockIdx.z * czstride, ldc, N,
             bias, boff, mode, bf, &lA[0][0], &lB[0][0]);
}

// ---------------------------------------------------------------------------
// Fused conv + x_proj split-K GEMM (verified in megakernel P3).
// Grid (32 m, 16 z): block computes SiLU(conv(xz)) for exactly its A-tile
// (rows m*64..+63, channels z*128..+127; partition, zero redundancy), then
// stages it from global (own-block visibility via __syncthreads) and GEMMs.
// ---------------------------------------------------------------------------
__global__ __launch_bounds__(256) void k_conv_xproj(
    const unsigned short* __restrict__ xz,
    const void* __restrict__ cw, size_t cwoff,
    const void* __restrict__ cb, size_t cboff,
    unsigned short* __restrict__ uc,
    const void* __restrict__ xpw, size_t woff,
    const unsigned short* __restrict__ w_xp,
    float* __restrict__ partsX,
    const int* __restrict__ flagp)
{
    __shared__ unsigned short lA[3][64 * 32];
    __shared__ unsigned short lB[3][128 * 32];
    const bool bf = (*flagp != 0);
    const int tid = threadIdx.x;
    const int m = blockIdx.x, z = blockIdx.y;
    const int dd = z * 128 + (tid & 127);
    const size_t cwo = cwoff + (size_t)dd * 4;
    const float w0 = ldin(cw, cwo + 0, bf), w1 = ldin(cw, cwo + 1, bf);
    const float w2 = ldin(cw, cwo + 2, bf), w3 = ldin(cw, cwo + 3, bf);
    const float cbv = ldin(cb, cboff + dd, bf);
    for (int it = 0; it < 32; ++it) {
        const int l = m * 64 + it * 2 + (tid >> 7);
        float acc = cbv;
        if (l >= 3) acc = fmaf(bf2f(xz[(size_t)(l - 3) * (2 * DINNER) + dd]), w0, acc);
        if (l >= 2) acc = fmaf(bf2f(xz[(size_t)(l - 2) * (2 * DINNER) + dd]), w1, acc);
        if (l >= 1) acc = fmaf(bf2f(xz[(size_t)(l - 1) * (2 * DINNER) + dd]), w2, acc);
        acc = fmaf(bf2f(xz[(size_t)l * (2 * DINNER) + dd]), w3, acc);
        const float sig = 1.f / (1.f + __expf(-acc));
        uc[(size_t)l * DINNER + dd] = f2bf(acc * sig);
    }
    __syncthreads();   // own uc writes complete before own gload16 reads
    const unsigned short* W = bf ? ((const unsigned short*)xpw + woff) : w_xp;
    gemm_dev(tid, 0, m * 64, z * 128, DINNER / KSPLIT,
             uc, DINNER, W, DINNER,
             partsX, (size_t)z * L_SEQ * XDIM, XDIM, XDIM,
             nullptr, 0, 0, bf, &lA[0][0], &lB[0][0]);
}

// ---------------------------------------------------------------------------
// x_proj split-K reduce: xdbl = sum of KSPLIT partials; dual write fp32+bf16.
// ---------------------------------------------------------------------------
__global__ __launch_bounds__(256) void k_reduce(
    const float* __restrict__ parts, float* __restrict__ xdbl,
    unsigned short* __restrict__ xdbl_bf)
{
    const int idx = blockIdx.x * 256 + threadIdx.x;
    float s = 0.f;
    #pragma unroll
    for (int z = 0; z < KSPLIT; ++z)
        s += parts[(size_t)z * L_SEQ * XDIM + idx];
    xdbl[idx] = s;
    xdbl_bf[idx] = f2bf(s);
}

// ---------------------------------------------------------------------------
// Chunked selective scan, pass 1: local scan from h=0 per (channels, chunk).
// ---------------------------------------------------------------------------
__global__ __launch_bounds__(128) void k_scan1(
    const float* __restrict__ delta, const unsigned short* __restrict__ uc,
    const float* __restrict__ xdbl,
    const void* __restrict__ Alog, size_t aoff,
    float* __restrict__ hloc, float* __restrict__ sdelta,
    const int* __restrict__ flagp)
{
    const bool bf = (*flagp != 0);
    __shared__ float sB[CHUNK][DSTATE];
    const int d = blockIdx.x * 128 + threadIdx.x;
    const int c = blockIdx.y;
    const int t0 = c * CHUNK;
    float A2[DSTATE];
    #pragma unroll
    for (int n = 0; n < DSTATE; ++n)
        A2[n] = -__expf(ldin(Alog, aoff + (size_t)d * DSTATE + n, bf)) * LOG2E;
    #pragma unroll
    for (int r = 0; r < 4; ++r) {
        const int idx = r * 128 + threadIdx.x;   // 0..511
        const int tt = idx >> 4, n = idx & 15;
        sB[tt][n] = xdbl[(size_t)(t0 + tt) * XDIM + DTRANK + n];
    }
    __syncthreads();
    float h[DSTATE];
    #pragma unroll
    for (int n = 0; n < DSTATE; ++n) h[n] = 0.f;
    float sd = 0.f;
    float dcur = delta[(size_t)t0 * DINNER + d];
    float ucur = bf2f(uc[(size_t)t0 * DINNER + d]);
    for (int ti = 0; ti < CHUNK; ++ti) {
        float dnx = 0.f, unx = 0.f;
        if (ti < CHUNK - 1) {
            const size_t nxt = (size_t)(t0 + ti + 1) * DINNER + d;
            dnx = delta[nxt];
            unx = bf2f(uc[nxt]);
        }
        sd += dcur;
        const float du = dcur * ucur;
        #pragma unroll
        for (int n = 0; n < DSTATE; ++n) {
            const float dA = exp2f(dcur * A2[n]);
            h[n] = fmaf(dA, h[n], du * sB[ti][n]);
        }
        dcur = dnx; ucur = unx;
    }
    float* hp = hloc + ((size_t)c * DINNER + d) * DSTATE;
    #pragma unroll
    for (int n = 0; n < DSTATE; n += 4)
        *(float4*)(hp + n) = make_float4(h[n], h[n + 1], h[n + 2], h[n + 3]);
    sdelta[(size_t)c * DINNER + d] = sd;
}

// ---------------------------------------------------------------------------
// Pass 2: per (d,n) sequential scan over chunk states; in-place -> Hin[c].
// 8-deep ping-pong register prefetch (static indexing).
// ---------------------------------------------------------------------------
__global__ __launch_bounds__(128) void k_scan2(
    float* __restrict__ hloc, const float* __restrict__ sdelta,
    const void* __restrict__ Alog, size_t aoff,
    const int* __restrict__ flagp)
{
    const bool bf = (*flagp != 0);
    const int gid = blockIdx.x * 128 + threadIdx.x;
    const int d = gid >> 4, n = gid & 15;
    const float A2 = -__expf(ldin(Alog, aoff + (size_t)d * DSTATE + n, bf)) * LOG2E;
    const size_t hstep = (size_t)DINNER * DSTATE;
    float* hp = hloc + (size_t)d * DSTATE + n;
    const float* sp = sdelta + d;
    float hA[8], sA[8], hB[8], sB[8];
    #pragma unroll
    for (int j = 0; j < 8; ++j) {
        hA[j] = hp[(size_t)j * hstep];
        sA[j] = sp[(size_t)j * DINNER];
    }
    float carry = 0.f;
    for (int g = 0; g < 8; g += 2) {
        const int cA = g * 8, cB = cA + 8, cN = cA + 16;
        #pragma unroll
        for (int j = 0; j < 8; ++j) {              // prefetch group g+1
            hB[j] = hp[(size_t)(cB + j) * hstep];
            sB[j] = sp[(size_t)(cB + j) * DINNER];
        }
        #pragma unroll
        for (int j = 0; j < 8; ++j) {              // compute group g
            hp[(size_t)(cA + j) * hstep] = carry;
            carry = fmaf(exp2f(A2 * sA[j]), carry, hA[j]);
        }
        if (g + 2 < 8) {
            #pragma unroll
            for (int j = 0; j < 8; ++j) {          // prefetch group g+2
                hA[j] = hp[(size_t)(cN + j) * hstep];
                sA[j] = sp[(size_t)(cN + j) * DINNER];
            }
        }
        #pragma unroll
        for (int j = 0; j < 8; ++j) {              // compute group g+1
            hp[(size_t)(cB + j) * hstep] = carry;
            carry = fmaf(exp2f(A2 * sB[j]), carry, hB[j]);
        }
    }
}

// ---------------------------------------------------------------------------
// Pass 3: local scan seeded with Hin[c]; y=(C.h+uc*D)*silu(z) as bf16.
// ---------------------------------------------------------------------------
__global__ __launch_bounds__(128) void k_scan3(
    const float* __restrict__ delta, const unsigned short* __restrict__ uc,
    const unsigned short* __restrict__ xz, const float* __restrict__ xdbl,
    const void* __restrict__ Alog, size_t aoff,
    const void* __restrict__ Dp, size_t doff,
    const float* __restrict__ hin, unsigned short* __restrict__ y,
    const int* __restrict__ flagp)
{
    const bool bf = (*flagp != 0);
    __shared__ float sBC[CHUNK][2 * DSTATE];
    const int d = blockIdx.x * 128 + threadIdx.x;
    const int c = blockIdx.y;
    const int t0 = c * CHUNK;
    float A2[DSTATE];
    #pragma unroll
    for (int n = 0; n < DSTATE; ++n)
        A2[n] = -__expf(ldin(Alog, aoff + (size_t)d * DSTATE + n, bf)) * LOG2E;
    const float Dv = ldin(Dp, doff + d, bf);
    #pragma unroll
    for (int r = 0; r < 8; ++r) {
        const int idx = r * 128 + threadIdx.x;   // 0..1023
        const int tt = idx >> 5, n = idx & 31;
        sBC[tt][n] = xdbl[(size_t)(t0 + tt) * XDIM + DTRANK + n];
    }
    __syncthreads();
    float h[DSTATE];
    const float* hp = hin + ((size_t)c * DINNER + d) * DSTATE;
    #pragma unroll
    for (int n = 0; n < DSTATE; n += 4) {
        const float4 v = *(const float4*)(hp + n);
        h[n] = v.x; h[n + 1] = v.y; h[n + 2] = v.z; h[n + 3] = v.w;
    }
    float dcur = delta[(size_t)t0 * DINNER + d];
    float ucur = bf2f(uc[(size_t)t0 * DINNER + d]);
    float zcur = bf2f(xz[(size_t)t0 * (2 * DINNER) + DINNER + d]);
    for (int ti = 0; ti < CHUNK; ++ti) {
        float dnx = 0.f, unx = 0.f, znx = 0.f;
        if (ti < CHUNK - 1) {
            const size_t nxt = (size_t)(t0 + ti + 1) * DINNER + d;
            dnx = delta[nxt];
            unx = bf2f(uc[nxt]);
            znx = bf2f(xz[(size_t)(t0 + ti + 1) * (2 * DINNER) + DINNER + d]);
        }
        const float du = dcur * ucur;
        float dot = 0.f;
        #pragma unroll
        for (int n = 0; n < DSTATE; ++n) {
            const float dA = exp2f(dcur * A2[n]);
            h[n] = fmaf(dA, h[n], du * sBC[ti][n]);
            dot = fmaf(h[n], sBC[ti][DSTATE + n], dot);
        }
        const float sig = 1.f / (1.f + __expf(-zcur));
        y[(size_t)(t0 + ti) * DINNER + d] = f2bf((dot + ucur * Dv) * (zcur * sig));
        dcur = dnx; ucur = unx; zcur = znx;
    }
}

// ---------------------------------------------------------------------------
// Final: out = (parts0..3) + residual, dtype per flag
// ---------------------------------------------------------------------------
__global__ __launch_bounds__(256) void k_final(
    const float* __restrict__ parts, const float* __restrict__ resid,
    void* __restrict__ out, const int* __restrict__ flagp)
{
    const bool bf = (*flagp != 0);
    const int i = (blockIdx.x * 256 + threadIdx.x) * 4;
    const float4 p0 = *(const float4*)(parts + i);
    const float4 p1 = *(const float4*)(parts + (size_t)1 * L_SEQ * DMODEL + i);
    const float4 p2 = *(const float4*)(parts + (size_t)2 * L_SEQ * DMODEL + i);
    const float4 p3 = *(const float4*)(parts + (size_t)3 * L_SEQ * DMODEL + i);
    const float4 rv = *(const float4*)(resid + i);
    const float o0 = p0.x + p1.x + p2.x + p3.x + rv.x;
    const float o1 = p0.y + p1.y + p2.y + p3.y + rv.y;
    const float o2 = p0.z + p1.z + p2.z + p3.z + rv.z;
    const float o3 = p0.w + p1.w + p2.w + p3.w + rv.w;
    if (bf) {
        ushort4 o;
        o.x = f2bf(o0); o.y = f2bf(o1); o.z = f2bf(o2); o.w = f2bf(o3);
        *(ushort4*)((unsigned short*)out + i) = o;
    } else {
        *(float4*)((float*)out + i) = make_float4(o0, o1, o2, o3);
    }
}

extern "C" void kernel_launch(void* const* d_in, const int* in_sizes, int n_in,
                              void* d_out, int out_size, void* d_ws, size_t ws_size,
                              hipStream_t stream)
{
    const void* hs    = d_in[0];
    const void* normw = d_in[1];
    const void* ipw   = d_in[2];
    const void* cw    = d_in[3];
    const void* cb    = d_in[4];
    const void* xpw   = d_in[5];
    const void* dtw   = d_in[6];
    const void* dtb   = d_in[7];
    const void* Alog  = d_in[8];
    const void* Dp    = d_in[9];
    const void* opw   = d_in[10];

    // fp32 region
    float* ws      = (float*)d_ws;
    float* resid   = ws;                                         // 2,097,152
    float* xdblb   = resid   + (size_t)L_SEQ * DMODEL;           //   196,608
    float* deltab  = xdblb   + (size_t)L_SEQ * XDIM;             // 4,194,304 (partsX overlay)
    float* hlocb   = deltab  + (size_t)L_SEQ * DINNER;           // 2,097,152
    float* sdeltab = hlocb   + (size_t)NCHUNK * DINNER * DSTATE; //   131,072
    float* partsO  = sdeltab + (size_t)NCHUNK * DINNER;          // 8,388,608 (4 slices)
    // bf16 region
    unsigned short* hn_bf   = (unsigned short*)(partsO + (size_t)KSPLIT_O * L_SEQ * DMODEL);
    unsigned short* xz_bf   = hn_bf   + (size_t)L_SEQ * DMODEL;
    unsigned short* uc_bf   = xz_bf   + (size_t)L_SEQ * 2 * DINNER;
    unsigned short* xdbl_bf = uc_bf   + (size_t)L_SEQ * DINNER;
    unsigned short* y_bf    = xdbl_bf + (size_t)L_SEQ * XDIM;
    unsigned short* w_ip    = y_bf    + (size_t)L_SEQ * DINNER;
    unsigned short* w_xp    = w_ip    + (size_t)NLAYER * N_IP;
    unsigned short* w_dt    = w_xp    + (size_t)NLAYER * N_XP;
    unsigned short* w_op    = w_dt    + (size_t)NLAYER * N_DT;
    int*            flagp   = (int*)(w_op + (size_t)NLAYER * N_OP);

    float* partsX = deltab;   // KSPLIT*L*XDIM = 3,145,728 <= 4,194,304
                              // (dead before dt_proj writes deltab)

    k_detect<<<1, 1, 0, stream>>>((const unsigned int*)Alog, flagp);
    k_castall<<<dim3(CAST_BLOCKS, NLAYER), 256, 0, stream>>>(
        ipw, xpw, dtw, opw, w_ip, w_xp, w_dt, w_op, flagp);

    for (int i = 0; i < NLAYER; ++i) {
        const size_t o_ipw = (size_t)i * N_IP;
        const size_t o_xpw = (size_t)i * N_XP;
        const size_t o_dtw = (size_t)i * N_DT;
        const size_t o_opw = (size_t)i * N_OP;
        const size_t o_al  = (size_t)i * DINNER * DSTATE;

        k_addnorm<<<L_SEQ, 256, 0, stream>>>(
            partsO, hs, resid, hn_bf, normw, (size_t)i * DMODEL, i == 0 ? 1 : 0, flagp);
        // in_proj: (2048 x 1024) @ (4096 x 1024)^T -> xz bf16  [1024 blocks]
        k_gemm_mfma<<<dim3(32, 32, 1), 256, 0, stream>>>(
            hn_bf, DMODEL, ipw, o_ipw, w_ip + o_ipw, DMODEL,
            xz_bf, 2 * DINNER, 0, 2 * DINNER, DMODEL, nullptr, 0, 2, flagp);
        // fused conv + x_proj split-K=16 (512 blocks = 32m x 16z)
        k_conv_xproj<<<dim3(32, KSPLIT), 256, 0, stream>>>(
            xz_bf, cw, (size_t)i * DINNER * DCONV, cb, (size_t)i * DINNER, uc_bf,
            xpw, o_xpw, w_xp + o_xpw, partsX, flagp);
        k_reduce<<<(L_SEQ * XDIM) / 256, 256, 0, stream>>>(partsX, xdblb, xdbl_bf);
        // dt_proj + softplus: (2048 x 96[:64]) @ (2048 x 64)^T -> delta fp32
        k_gemm_mfma<<<dim3(16, 32, 1), 256, 0, stream>>>(
            xdbl_bf, XDIM, dtw, o_dtw, w_dt + o_dtw, DTRANK,
            deltab, DINNER, 0, DINNER, DTRANK, dtb, (size_t)i * DINNER, 1, flagp);
        // chunk-parallel selective scan
        k_scan1<<<dim3(DINNER / 128, NCHUNK), 128, 0, stream>>>(
            deltab, uc_bf, xdblb, Alog, o_al, hlocb, sdeltab, flagp);
        k_scan2<<<(DINNER * DSTATE) / 128, 128, 0, stream>>>(
            hlocb, sdeltab, Alog, o_al, flagp);
        k_scan3<<<dim3(DINNER / 128, NCHUNK), 128, 0, stream>>>(
            deltab, uc_bf, xz_bf, xdblb, Alog, o_al, Dp, (size_t)i * DINNER,
            hlocb, y_bf, flagp);
        // out_proj split-K=4: (2048 x 2048) @ (1024 x 2048)^T -> 4 partials
        k_gemm_mfma<<<dim3(8, 32, KSPLIT_O), 256, 0, stream>>>(
            y_bf, DINNER, opw, o_opw, w_op + o_opw, DINNER,
            partsO, DMODEL, (size_t)L_SEQ * DMODEL, DMODEL, DINNER / KSPLIT_O,
            nullptr, 0, 0, flagp);
    }
    k_final<<<(L_SEQ * DMODEL) / 1024, 256, 0, stream>>>(partsO, resid, d_out, flagp);
}